// Round 1
// baseline (11279.103 us; speedup 1.0000x reference)
//
#include <hip/hip_runtime.h>
#include <stdint.h>

#define L_SEQ 4096
#define EDIM  1024
#define HDIM  4096
#define NLAY  8

typedef unsigned short u16;
typedef __attribute__((ext_vector_type(8))) short short8;
typedef __attribute__((ext_vector_type(4))) float f32x4;

static __device__ __forceinline__ u16 f2b(float f) {
  union { float f; uint32_t u; } a; a.f = f;
  uint32_t u = a.u;
  return (u16)((u + 0x7FFFu + ((u >> 16) & 1u)) >> 16);  // RNE
}
static __device__ __forceinline__ float b2f(u16 b) {
  union { uint32_t u; float f; } a; a.u = ((uint32_t)b) << 16;
  return a.f;
}

// x[t,e] = embed[tok[t], e], tok[0]=0, tok[t]=s[t-1]
__global__ void k_embed(const int* __restrict__ s, const float* __restrict__ embed,
                        float* __restrict__ x) {
  int i = blockIdx.x * blockDim.x + threadIdx.x;  // over L*E
  int t = i >> 10, e = i & 1023;
  int tok = (t == 0) ? 0 : s[t - 1];
  x[i] = embed[tok * EDIM + e];
}

__global__ void k_mix3(const float* __restrict__ x,
                       const float* __restrict__ mk, const float* __restrict__ mv,
                       const float* __restrict__ mr,
                       u16* __restrict__ kx, u16* __restrict__ vx, u16* __restrict__ rx) {
  int i = blockIdx.x * blockDim.x + threadIdx.x;
  int e = i & 1023;
  float xc = x[i];
  float xs = (i >= EDIM) ? x[i - EDIM] : 0.f;
  float a = mk[e]; kx[i] = f2b(xc * a + xs * (1.f - a));
  a = mv[e];       vx[i] = f2b(xc * a + xs * (1.f - a));
  a = mr[e];       rx[i] = f2b(xc * a + xs * (1.f - a));
}

__global__ void k_mix2(const float* __restrict__ x,
                       const float* __restrict__ mk, const float* __restrict__ mr,
                       u16* __restrict__ kx, u16* __restrict__ rx) {
  int i = blockIdx.x * blockDim.x + threadIdx.x;
  int e = i & 1023;
  float xc = x[i];
  float xs = (i >= EDIM) ? x[i - EDIM] : 0.f;
  float a = mk[e]; kx[i] = f2b(xc * a + xs * (1.f - a));
  a = mr[e];       rx[i] = f2b(xc * a + xs * (1.f - a));
}

// C[M,N] = A_bf16[M,K] @ B_f32[K,N] (B converted to bf16 on the fly)
// EPI: 0 = store f32, 1 = C += (f32), 2 = store bf16 of relu(v)^2
template <int EPI>
__global__ __launch_bounds__(256)
void k_gemm(const u16* __restrict__ A, const float* __restrict__ B,
            void* __restrict__ Cv, int N, int K) {
  constexpr int LDS_STR = 40;  // 80B row stride: 16B-aligned, 2-way bank aliasing only
  __shared__ __align__(16) u16 As[128 * LDS_STR];
  __shared__ __align__(16) u16 Bs[128 * LDS_STR];  // Bs[n][k]
  const int bm = blockIdx.y * 128, bn = blockIdx.x * 128;
  const int tid = threadIdx.x;
  const int lane = tid & 63, w = tid >> 6;
  const int wr = w >> 1, wc = w & 1;      // 2x2 wave grid, 64x64 per wave
  const int l16 = lane & 15, lhi = lane >> 4;

  f32x4 acc[4][4];
#pragma unroll
  for (int a = 0; a < 4; ++a)
#pragma unroll
    for (int b = 0; b < 4; ++b)
#pragma unroll
      for (int r = 0; r < 4; ++r) acc[a][b][r] = 0.f;

  const int ar = tid >> 1, ak = (tid & 1) * 16;   // A stage: row, k-offset
  const int bk = tid >> 5, bn4 = (tid & 31) * 4;  // B stage: k-row, n-offset

  for (int k0 = 0; k0 < K; k0 += 32) {
    {  // stage A tile [128 x 32] bf16
      const uint4* src = reinterpret_cast<const uint4*>(A + (size_t)(bm + ar) * K + k0 + ak);
      uint4 v0 = src[0], v1 = src[1];
      uint4* dst = reinterpret_cast<uint4*>(&As[ar * LDS_STR + ak]);
      dst[0] = v0; dst[1] = v1;
    }
#pragma unroll
    for (int i = 0; i < 4; ++i) {  // stage B tile [32 x 128] f32 -> bf16 transposed
      int kr = bk + i * 8;
      const float4 bv = *reinterpret_cast<const float4*>(B + (size_t)(k0 + kr) * N + bn + bn4);
      Bs[(bn4 + 0) * LDS_STR + kr] = f2b(bv.x);
      Bs[(bn4 + 1) * LDS_STR + kr] = f2b(bv.y);
      Bs[(bn4 + 2) * LDS_STR + kr] = f2b(bv.z);
      Bs[(bn4 + 3) * LDS_STR + kr] = f2b(bv.w);
    }
    __syncthreads();
    short8 af[4], bfr[4];
#pragma unroll
    for (int mi = 0; mi < 4; ++mi)
      af[mi] = *reinterpret_cast<const short8*>(&As[(wr * 64 + mi * 16 + l16) * LDS_STR + lhi * 8]);
#pragma unroll
    for (int ni = 0; ni < 4; ++ni)
      bfr[ni] = *reinterpret_cast<const short8*>(&Bs[(wc * 64 + ni * 16 + l16) * LDS_STR + lhi * 8]);
#pragma unroll
    for (int mi = 0; mi < 4; ++mi)
#pragma unroll
      for (int ni = 0; ni < 4; ++ni)
        acc[mi][ni] = __builtin_amdgcn_mfma_f32_16x16x32_bf16(af[mi], bfr[ni], acc[mi][ni], 0, 0, 0);
    __syncthreads();
  }
#pragma unroll
  for (int mi = 0; mi < 4; ++mi)
#pragma unroll
    for (int ni = 0; ni < 4; ++ni)
#pragma unroll
      for (int r = 0; r < 4; ++r) {
        int row = bm + wr * 64 + mi * 16 + lhi * 4 + r;
        int col = bn + wc * 64 + ni * 16 + l16;
        size_t o = (size_t)row * N + col;
        float v = acc[mi][ni][r];
        if constexpr (EPI == 0) ((float*)Cv)[o] = v;
        else if constexpr (EPI == 1) ((float*)Cv)[o] += v;
        else { v = fmaxf(v, 0.f); ((u16*)Cv)[o] = f2b(v * v); }
      }
}

// max-stabilized WKV recurrence; one thread per channel
__global__ void k_wkv(const float* __restrict__ k, const float* __restrict__ v,
                      const float* __restrict__ u_, const float* __restrict__ w_,
                      float* __restrict__ out) {
  int e = blockIdx.x * blockDim.x + threadIdx.x;
  float u = u_[e];
  float D = __expf(w_[e]);
  float aa = 0.f, bb = 0.f, pp = -__builtin_inff();
#pragma unroll 4
  for (int t = 0; t < L_SEQ; ++t) {
    float kk = k[t * EDIM + e];
    float vv = v[t * EDIM + e];
    float ww = u + kk;
    float p = fmaxf(pp, ww);
    float e1 = __expf(pp - p);
    float e2 = __expf(ww - p);
    out[t * EDIM + e] = (e1 * aa + e2 * vv) / (e1 * bb + e2);
    float w2 = pp - D;
    float p2 = fmaxf(w2, kk);
    float e1b = __expf(w2 - p2);
    float e2b = __expf(kk - p2);
    aa = e1b * aa + e2b * vv;
    bb = e1b * bb + e2b;
    pp = p2;
  }
}

__global__ void k_gate_mul(const float* __restrict__ rpre, const float* __restrict__ wkv,
                           u16* __restrict__ outb) {
  int i = blockIdx.x * blockDim.x + threadIdx.x;
  float r = 1.f / (1.f + __expf(-rpre[i]));
  outb[i] = f2b(r * wkv[i]);
}

__global__ void k_gate_add(float* __restrict__ x, const float* __restrict__ rpre,
                           const float* __restrict__ t) {
  int i = blockIdx.x * blockDim.x + threadIdx.x;
  float r = 1.f / (1.f + __expf(-rpre[i]));
  x[i] += r * t[i];
}

__global__ void k_cast(const float* __restrict__ x, u16* __restrict__ o) {
  int i = blockIdx.x * blockDim.x + threadIdx.x;
  o[i] = f2b(x[i]);
}

__global__ void k_gelu(const float* __restrict__ p, const float* __restrict__ b,
                       u16* __restrict__ o) {
  int i = blockIdx.x * blockDim.x + threadIdx.x;
  int e = i & 1023;
  float v = p[i] + b[e];
  float c = 0.7978845608028654f * (v + 0.044715f * v * v * v);
  float g = 0.5f * v * (1.f + tanhf(c));
  o[i] = f2b(g);
}

// per-token: logits[4] = h_row @ W[E,4]; partial[t] = 0.5*logsoftmax(logits)[s[t]]
__global__ __launch_bounds__(256)
void k_head(const u16* __restrict__ h, const float* __restrict__ W,
            const int* __restrict__ s, float* __restrict__ partial) {
  int t = blockIdx.x, tid = threadIdx.x;
  float a0 = 0.f, a1 = 0.f, a2 = 0.f, a3 = 0.f;
  for (int e = tid; e < EDIM; e += 256) {
    float hv = b2f(h[t * EDIM + e]);
    const float4 wv = *reinterpret_cast<const float4*>(W + e * 4);
    a0 += hv * wv.x; a1 += hv * wv.y; a2 += hv * wv.z; a3 += hv * wv.w;
  }
#pragma unroll
  for (int off = 32; off > 0; off >>= 1) {
    a0 += __shfl_down(a0, off, 64);
    a1 += __shfl_down(a1, off, 64);
    a2 += __shfl_down(a2, off, 64);
    a3 += __shfl_down(a3, off, 64);
  }
  __shared__ float sm[4][4];
  int w = tid >> 6, lane = tid & 63;
  if (lane == 0) { sm[w][0] = a0; sm[w][1] = a1; sm[w][2] = a2; sm[w][3] = a3; }
  __syncthreads();
  if (tid == 0) {
    float lg[4];
#pragma unroll
    for (int j = 0; j < 4; ++j) lg[j] = sm[0][j] + sm[1][j] + sm[2][j] + sm[3][j];
    float m = fmaxf(fmaxf(lg[0], lg[1]), fmaxf(lg[2], lg[3]));
    float sum = expf(lg[0] - m) + expf(lg[1] - m) + expf(lg[2] - m) + expf(lg[3] - m);
    partial[t] = 0.5f * (lg[s[t]] - m - logf(sum));
  }
}

__global__ __launch_bounds__(256)
void k_reduce(const float* __restrict__ partial, float* __restrict__ out) {
  int tid = threadIdx.x;
  float a = 0.f;
  for (int j = tid; j < L_SEQ; j += 256) a += partial[j];
#pragma unroll
  for (int off = 32; off > 0; off >>= 1) a += __shfl_down(a, off, 64);
  __shared__ float sm[4];
  if ((tid & 63) == 0) sm[tid >> 6] = a;
  __syncthreads();
  if (tid == 0) out[0] = sm[0] + sm[1] + sm[2] + sm[3];
}

extern "C" void kernel_launch(void* const* d_in, const int* in_sizes, int n_in,
                              void* d_out, int out_size, void* d_ws, size_t ws_size,
                              hipStream_t stream) {
  const int*   s        = (const int*)d_in[0];
  const float* embed    = (const float*)d_in[1];
  const float* tm_first = (const float*)d_in[2];
  const float* tm_decay = (const float*)d_in[3];
  const float* tm_mk    = (const float*)d_in[4];
  const float* tm_mv    = (const float*)d_in[5];
  const float* tm_mr    = (const float*)d_in[6];
  const float* tm_Wk    = (const float*)d_in[7];
  const float* tm_Wv    = (const float*)d_in[8];
  const float* tm_Wr    = (const float*)d_in[9];
  const float* tm_Wo    = (const float*)d_in[10];
  const float* cm_mk    = (const float*)d_in[11];
  const float* cm_mr    = (const float*)d_in[12];
  const float* cm_Wk    = (const float*)d_in[13];
  const float* cm_Wr    = (const float*)d_in[14];
  const float* cm_Wv    = (const float*)d_in[15];
  const float* neck_W   = (const float*)d_in[16];
  const float* neck_b   = (const float*)d_in[17];
  const float* head_W   = (const float*)d_in[18];

  char* ws = (char*)d_ws;
  size_t off = 0;
  auto alloc = [&](size_t bytes) { char* p = ws + off; off += (bytes + 255) & ~(size_t)255; return p; };
  const size_t LE4 = (size_t)L_SEQ * EDIM * 4, LE2 = (size_t)L_SEQ * EDIM * 2;
  float* x     = (float*)alloc(LE4);
  u16*   kxb   = (u16*)alloc(LE2);
  u16*   vxb   = (u16*)alloc(LE2);   // also rwb / hb
  u16*   rxb   = (u16*)alloc(LE2);
  float* kf    = (float*)alloc(LE4); // also neck pre-act
  float* vf    = (float*)alloc(LE4);
  float* rpre  = (float*)alloc(LE4);
  float* wkvf  = (float*)alloc(LE4); // also cm tmp
  u16*   kkb   = (u16*)alloc((size_t)L_SEQ * HDIM * 2);
  float* partial = (float*)alloc((size_t)L_SEQ * 4);

  const dim3 blk(256);
  const dim3 gE((L_SEQ * EDIM) / 256);
  const dim3 gemmE(EDIM / 128, L_SEQ / 128);
  const dim3 gemmH(HDIM / 128, L_SEQ / 128);

  k_embed<<<gE, blk, 0, stream>>>(s, embed, x);
  for (int l = 0; l < NLAY; ++l) {
    size_t oE  = (size_t)l * EDIM;
    size_t oEE = (size_t)l * EDIM * EDIM;
    size_t oEH = (size_t)l * EDIM * HDIM;
    // --- TimeMixing ---
    k_mix3<<<gE, blk, 0, stream>>>(x, tm_mk + oE, tm_mv + oE, tm_mr + oE, kxb, vxb, rxb);
    k_gemm<0><<<gemmE, blk, 0, stream>>>(kxb, tm_Wk + oEE, kf, EDIM, EDIM);
    k_gemm<0><<<gemmE, blk, 0, stream>>>(vxb, tm_Wv + oEE, vf, EDIM, EDIM);
    k_gemm<0><<<gemmE, blk, 0, stream>>>(rxb, tm_Wr + oEE, rpre, EDIM, EDIM);
    k_wkv<<<dim3(EDIM / 256), blk, 0, stream>>>(kf, vf, tm_first + oE, tm_decay + oE, wkvf);
    k_gate_mul<<<gE, blk, 0, stream>>>(rpre, wkvf, vxb);               // rwb := vxb
    k_gemm<1><<<gemmE, blk, 0, stream>>>(vxb, tm_Wo + oEE, x, EDIM, EDIM);  // x +=
    // --- ChannelMixing ---
    k_mix2<<<gE, blk, 0, stream>>>(x, cm_mk + oE, cm_mr + oE, kxb, rxb);
    k_gemm<0><<<gemmE, blk, 0, stream>>>(rxb, cm_Wr + oEE, rpre, EDIM, EDIM);
    k_gemm<2><<<gemmH, blk, 0, stream>>>(kxb, cm_Wk + oEH, kkb, HDIM, EDIM);  // sqrelu bf16
    k_gemm<0><<<gemmE, blk, 0, stream>>>(kkb, cm_Wv + oEH, wkvf, EDIM, HDIM);
    k_gate_add<<<gE, blk, 0, stream>>>(x, rpre, wkvf);                 // x += sig(r)*tmp
  }
  // --- Neck + Head ---
  k_cast<<<gE, blk, 0, stream>>>(x, kxb);
  k_gemm<0><<<gemmE, blk, 0, stream>>>(kxb, neck_W, kf, EDIM, EDIM);
  k_gelu<<<gE, blk, 0, stream>>>(kf, neck_b, vxb);
  k_head<<<dim3(L_SEQ), blk, 0, stream>>>(vxb, head_W, s, partial);
  k_reduce<<<dim3(1), blk, 0, stream>>>(partial, (float*)d_out);

  (void)in_sizes; (void)n_in; (void)out_size; (void)ws_size;
}

// Round 2
// 3173.220 us; speedup vs baseline: 3.5545x; 3.5545x over previous
//
#include <hip/hip_runtime.h>
#include <stdint.h>

#define L_SEQ 4096
#define EDIM  1024
#define HDIM  4096
#define NLAY  8
#define WKV_C 64   // chunks
#define WKV_T 64   // tokens per chunk

typedef unsigned short u16;
typedef __attribute__((ext_vector_type(8))) short short8;
typedef __attribute__((ext_vector_type(4))) float f32x4;

static __device__ __forceinline__ u16 f2b(float f) {
  union { float f; uint32_t u; } a; a.f = f;
  uint32_t u = a.u;
  return (u16)((u + 0x7FFFu + ((u >> 16) & 1u)) >> 16);  // RNE
}
static __device__ __forceinline__ float b2f(u16 b) {
  union { uint32_t u; float f; } a; a.u = ((uint32_t)b) << 16;
  return a.f;
}

static __device__ __forceinline__ void gld_lds16(const void* g, void* l) {
  __builtin_amdgcn_global_load_lds(
      (const __attribute__((address_space(1))) void*)g,
      (__attribute__((address_space(3))) void*)l, 16, 0, 0);
}

// ---------------- elementwise ----------------

__global__ void k_embed(const int* __restrict__ s, const float* __restrict__ embed,
                        float* __restrict__ x) {
  int i = blockIdx.x * blockDim.x + threadIdx.x;
  int t = i >> 10, e = i & 1023;
  int tok = (t == 0) ? 0 : s[t - 1];
  x[i] = embed[tok * EDIM + e];
}

__global__ void k_mix3(const float* __restrict__ x,
                       const float* __restrict__ mk, const float* __restrict__ mv,
                       const float* __restrict__ mr,
                       u16* __restrict__ kx, u16* __restrict__ vx, u16* __restrict__ rx) {
  int i = blockIdx.x * blockDim.x + threadIdx.x;
  int e = i & 1023;
  float xc = x[i];
  float xs = (i >= EDIM) ? x[i - EDIM] : 0.f;
  float a = mk[e]; kx[i] = f2b(xc * a + xs * (1.f - a));
  a = mv[e];       vx[i] = f2b(xc * a + xs * (1.f - a));
  a = mr[e];       rx[i] = f2b(xc * a + xs * (1.f - a));
}

__global__ void k_mix2(const float* __restrict__ x,
                       const float* __restrict__ mk, const float* __restrict__ mr,
                       u16* __restrict__ kx, u16* __restrict__ rx) {
  int i = blockIdx.x * blockDim.x + threadIdx.x;
  int e = i & 1023;
  float xc = x[i];
  float xs = (i >= EDIM) ? x[i - EDIM] : 0.f;
  float a = mk[e]; kx[i] = f2b(xc * a + xs * (1.f - a));
  a = mr[e];       rx[i] = f2b(xc * a + xs * (1.f - a));
}

__global__ void k_gate_mul(const float* __restrict__ rpre, const float* __restrict__ wkv,
                           u16* __restrict__ outb) {
  int i = blockIdx.x * blockDim.x + threadIdx.x;
  float r = 1.f / (1.f + __expf(-rpre[i]));
  outb[i] = f2b(r * wkv[i]);
}

__global__ void k_gate_add(float* __restrict__ x, const float* __restrict__ rpre,
                           const float* __restrict__ t) {
  int i = blockIdx.x * blockDim.x + threadIdx.x;
  float r = 1.f / (1.f + __expf(-rpre[i]));
  x[i] += r * t[i];
}

__global__ void k_cast(const float* __restrict__ x, u16* __restrict__ o) {
  int i = blockIdx.x * blockDim.x + threadIdx.x;
  o[i] = f2b(x[i]);
}

__global__ void k_gelu(const float* __restrict__ p, const float* __restrict__ b,
                       u16* __restrict__ o) {
  int i = blockIdx.x * blockDim.x + threadIdx.x;
  int e = i & 1023;
  float v = p[i] + b[e];
  float c = 0.7978845608028654f * (v + 0.044715f * v * v * v);
  float g = 0.5f * v * (1.f + tanhf(c));
  o[i] = f2b(g);
}

// transpose + f32->bf16: src [K][N] f32 (batched by z), dst [N][K] bf16
__global__ __launch_bounds__(256)
void k_tconv(const float* __restrict__ src, u16* __restrict__ dst, int K, int N) {
  __shared__ float tile[32][33];
  const float* s = src + (size_t)blockIdx.z * K * N;
  u16* d = dst + (size_t)blockIdx.z * K * N;
  int n0 = blockIdx.x * 32, k0 = blockIdx.y * 32;
  int tx = threadIdx.x & 31, ty = threadIdx.x >> 5;  // 32 x 8
#pragma unroll
  for (int i = 0; i < 32; i += 8)
    tile[ty + i][tx] = s[(size_t)(k0 + ty + i) * N + n0 + tx];
  __syncthreads();
#pragma unroll
  for (int i = 0; i < 32; i += 8)
    d[(size_t)(n0 + ty + i) * K + k0 + tx] = f2b(tile[tx][ty + i]);
}

// ---------------- GEMM: C[M,N] = A_bf16[M,K] @ Bt_bf16[N,K]^T ----------------
// EPI: 0 = store f32, 1 = C += f32, 2 = store bf16 of relu(v)^2
template <int EPI>
__device__ __forceinline__
void gemm_body(const u16* __restrict__ A, const u16* __restrict__ Bt,
               void* __restrict__ Cv, int N, int K, int bm, int bn) {
  __shared__ __align__(16) u16 As[128 * 32];
  __shared__ __align__(16) u16 Bs[128 * 32];
  const int tid = threadIdx.x, lane = tid & 63, w = tid >> 6;
  const int wr = w >> 1, wc = w & 1;
  const int l16 = lane & 15, lhi = lane >> 4;

  f32x4 acc[4][4];
#pragma unroll
  for (int a = 0; a < 4; ++a)
#pragma unroll
    for (int b = 0; b < 4; ++b)
#pragma unroll
      for (int r = 0; r < 4; ++r) acc[a][b][r] = 0.f;

  const size_t rowBytes = (size_t)K * 2;
  // staging: byte offset in 8KB tile = w*2048 + i*1024 + lane*16
  const int off0 = w * 2048 + lane * 16;

  for (int k0 = 0; k0 < K; k0 += 32) {
#pragma unroll
    for (int i = 0; i < 2; ++i) {
      const int off = off0 + i * 1024;
      const int row = off >> 6, cb = off & 63;
      gld_lds16((const char*)A + (size_t)(bm + row) * rowBytes + k0 * 2 + cb,
                &As[(w * 2048 + i * 1024) / 2]);
      gld_lds16((const char*)Bt + (size_t)(bn + row) * rowBytes + k0 * 2 + cb,
                &Bs[(w * 2048 + i * 1024) / 2]);
    }
    __syncthreads();
    short8 af[4], bfr[4];
#pragma unroll
    for (int mi = 0; mi < 4; ++mi)
      af[mi] = *reinterpret_cast<const short8*>(&As[(wr * 64 + mi * 16 + l16) * 32 + lhi * 8]);
#pragma unroll
    for (int ni = 0; ni < 4; ++ni)
      bfr[ni] = *reinterpret_cast<const short8*>(&Bs[(wc * 64 + ni * 16 + l16) * 32 + lhi * 8]);
#pragma unroll
    for (int mi = 0; mi < 4; ++mi)
#pragma unroll
      for (int ni = 0; ni < 4; ++ni)
        acc[mi][ni] = __builtin_amdgcn_mfma_f32_16x16x32_bf16(af[mi], bfr[ni], acc[mi][ni], 0, 0, 0);
    __syncthreads();
  }
#pragma unroll
  for (int mi = 0; mi < 4; ++mi)
#pragma unroll
    for (int ni = 0; ni < 4; ++ni)
#pragma unroll
      for (int r = 0; r < 4; ++r) {
        int row = bm + wr * 64 + mi * 16 + lhi * 4 + r;
        int col = bn + wc * 64 + ni * 16 + l16;
        size_t o = (size_t)row * N + col;
        float v = acc[mi][ni][r];
        if constexpr (EPI == 0) ((float*)Cv)[o] = v;
        else if constexpr (EPI == 1) ((float*)Cv)[o] += v;
        else { v = fmaxf(v, 0.f); ((u16*)Cv)[o] = f2b(v * v); }
      }
}

template <int EPI>
__global__ __launch_bounds__(256)
void k_gemm(const u16* __restrict__ A, const u16* __restrict__ Bt,
            void* __restrict__ Cv, int N, int K) {
  gemm_body<EPI>(A, Bt, Cv, N, K, blockIdx.y * 128, blockIdx.x * 128);
}

// batched: z selects (A, Bt, C) triple; same N, K
__global__ __launch_bounds__(256)
void k_gemm3(const u16* __restrict__ A0, const u16* __restrict__ A1, const u16* __restrict__ A2,
             const u16* __restrict__ B0, const u16* __restrict__ B1, const u16* __restrict__ B2,
             float* __restrict__ C0, float* __restrict__ C1, float* __restrict__ C2,
             int N, int K) {
  const u16* A = (blockIdx.z == 0) ? A0 : (blockIdx.z == 1) ? A1 : A2;
  const u16* B = (blockIdx.z == 0) ? B0 : (blockIdx.z == 1) ? B1 : B2;
  float*     C = (blockIdx.z == 0) ? C0 : (blockIdx.z == 1) ? C1 : C2;
  gemm_body<0>(A, B, C, N, K, blockIdx.y * 128, blockIdx.x * 128);
}

// ---------------- chunk-parallel WKV ----------------
// state (aa, bb, pp) represents N = aa*e^pp, Dn = bb*e^pp

__global__ void k_wkv_pass1(const float* __restrict__ k, const float* __restrict__ v,
                            const float* __restrict__ w_,
                            float* __restrict__ sa, float* __restrict__ sb,
                            float* __restrict__ sp) {
  int id = blockIdx.x * blockDim.x + threadIdx.x;  // over C*E
  int e = id & 1023, c = id >> 10;
  float D = __expf(w_[e]);
  float aa = 0.f, bb = 0.f, pp = -__builtin_inff();
  const float* kp = k + (size_t)c * WKV_T * EDIM + e;
  const float* vp = v + (size_t)c * WKV_T * EDIM + e;
#pragma unroll 4
  for (int i = 0; i < WKV_T; ++i) {
    float kk = kp[i * EDIM], vv = vp[i * EDIM];
    float ww = pp - D;
    float p2 = fmaxf(ww, kk);
    float e1 = __expf(ww - p2), e2 = __expf(kk - p2);
    aa = e1 * aa + e2 * vv;
    bb = e1 * bb + e2;
    pp = p2;
  }
  sa[id] = aa; sb[id] = bb; sp[id] = pp;
}

// exclusive scan over chunks (per channel); overwrites states with prefix
__global__ void k_wkv_scan(const float* __restrict__ w_,
                           float* __restrict__ sa, float* __restrict__ sb,
                           float* __restrict__ sp) {
  int e = blockIdx.x * blockDim.x + threadIdx.x;  // over E
  float DT = __expf(w_[e]) * (float)WKV_T;
  float A = 0.f, B = 0.f, P = -__builtin_inff();
  for (int c = 0; c < WKV_C; ++c) {
    int idx = c * EDIM + e;
    float a = sa[idx], b = sb[idx], q = sp[idx];
    sa[idx] = A; sb[idx] = B; sp[idx] = P;
    float shift = P - DT;
    float pn = fmaxf(shift, q);
    float w1 = __expf(shift - pn), w2 = __expf(q - pn);
    A = w1 * A + w2 * a;
    B = w1 * B + w2 * b;
    P = pn;
  }
}

__global__ void k_wkv_pass2(const float* __restrict__ k, const float* __restrict__ v,
                            const float* __restrict__ u_, const float* __restrict__ w_,
                            const float* __restrict__ sa, const float* __restrict__ sb,
                            const float* __restrict__ sp, float* __restrict__ out) {
  int id = blockIdx.x * blockDim.x + threadIdx.x;  // over C*E
  int e = id & 1023, c = id >> 10;
  float u = u_[e];
  float D = __expf(w_[e]);
  float aa = sa[id], bb = sb[id], pp = sp[id];
  const size_t base = (size_t)c * WKV_T * EDIM + e;
  const float* kp = k + base;
  const float* vp = v + base;
  float* op = out + base;
#pragma unroll 4
  for (int i = 0; i < WKV_T; ++i) {
    float kk = kp[i * EDIM], vv = vp[i * EDIM];
    float ww = u + kk;
    float p = fmaxf(pp, ww);
    float e1 = __expf(pp - p), e2 = __expf(ww - p);
    op[i * EDIM] = (e1 * aa + e2 * vv) / (e1 * bb + e2);
    float w2s = pp - D;
    float p2 = fmaxf(w2s, kk);
    float e1b = __expf(w2s - p2), e2b = __expf(kk - p2);
    aa = e1b * aa + e2b * vv;
    bb = e1b * bb + e2b;
    pp = p2;
  }
}

// ---------------- head ----------------

__global__ __launch_bounds__(256)
void k_head(const u16* __restrict__ h, const float* __restrict__ W,
            const int* __restrict__ s, float* __restrict__ partial) {
  int t = blockIdx.x, tid = threadIdx.x;
  float a0 = 0.f, a1 = 0.f, a2 = 0.f, a3 = 0.f;
  for (int e = tid; e < EDIM; e += 256) {
    float hv = b2f(h[t * EDIM + e]);
    const float4 wv = *reinterpret_cast<const float4*>(W + e * 4);
    a0 += hv * wv.x; a1 += hv * wv.y; a2 += hv * wv.z; a3 += hv * wv.w;
  }
#pragma unroll
  for (int off = 32; off > 0; off >>= 1) {
    a0 += __shfl_down(a0, off, 64);
    a1 += __shfl_down(a1, off, 64);
    a2 += __shfl_down(a2, off, 64);
    a3 += __shfl_down(a3, off, 64);
  }
  __shared__ float sm[4][4];
  int w = tid >> 6, lane = tid & 63;
  if (lane == 0) { sm[w][0] = a0; sm[w][1] = a1; sm[w][2] = a2; sm[w][3] = a3; }
  __syncthreads();
  if (tid == 0) {
    float lg[4];
#pragma unroll
    for (int j = 0; j < 4; ++j) lg[j] = sm[0][j] + sm[1][j] + sm[2][j] + sm[3][j];
    float m = fmaxf(fmaxf(lg[0], lg[1]), fmaxf(lg[2], lg[3]));
    float sum = expf(lg[0] - m) + expf(lg[1] - m) + expf(lg[2] - m) + expf(lg[3] - m);
    partial[t] = 0.5f * (lg[s[t]] - m - logf(sum));
  }
}

__global__ __launch_bounds__(256)
void k_reduce(const float* __restrict__ partial, float* __restrict__ out) {
  int tid = threadIdx.x;
  float a = 0.f;
  for (int j = tid; j < L_SEQ; j += 256) a += partial[j];
#pragma unroll
  for (int off = 32; off > 0; off >>= 1) a += __shfl_down(a, off, 64);
  __shared__ float sm[4];
  if ((tid & 63) == 0) sm[tid >> 6] = a;
  __syncthreads();
  if (tid == 0) out[0] = sm[0] + sm[1] + sm[2] + sm[3];
}

// ---------------- host ----------------

extern "C" void kernel_launch(void* const* d_in, const int* in_sizes, int n_in,
                              void* d_out, int out_size, void* d_ws, size_t ws_size,
                              hipStream_t stream) {
  const int*   s        = (const int*)d_in[0];
  const float* embed    = (const float*)d_in[1];
  const float* tm_first = (const float*)d_in[2];
  const float* tm_decay = (const float*)d_in[3];
  const float* tm_mk    = (const float*)d_in[4];
  const float* tm_mv    = (const float*)d_in[5];
  const float* tm_mr    = (const float*)d_in[6];
  const float* tm_Wk    = (const float*)d_in[7];
  const float* tm_Wv    = (const float*)d_in[8];
  const float* tm_Wr    = (const float*)d_in[9];
  const float* tm_Wo    = (const float*)d_in[10];
  const float* cm_mk    = (const float*)d_in[11];
  const float* cm_mr    = (const float*)d_in[12];
  const float* cm_Wk    = (const float*)d_in[13];
  const float* cm_Wr    = (const float*)d_in[14];
  const float* cm_Wv    = (const float*)d_in[15];
  const float* neck_W   = (const float*)d_in[16];
  const float* neck_b   = (const float*)d_in[17];
  const float* head_W   = (const float*)d_in[18];

  char* ws = (char*)d_ws;
  size_t off = 0;
  auto alloc = [&](size_t bytes) { char* p = ws + off; off += (bytes + 255) & ~(size_t)255; return p; };
  const size_t LE4 = (size_t)L_SEQ * EDIM * 4, LE2 = (size_t)L_SEQ * EDIM * 2;
  const size_t EE  = (size_t)EDIM * EDIM, EH = (size_t)EDIM * HDIM;

  float* x     = (float*)alloc(LE4);
  u16*   kxb   = (u16*)alloc(LE2);
  u16*   vxb   = (u16*)alloc(LE2);
  u16*   rxb   = (u16*)alloc(LE2);
  float* kf    = (float*)alloc(LE4);
  float* vf    = (float*)alloc(LE4);
  float* rpre  = (float*)alloc(LE4);
  float* wkvf  = (float*)alloc(LE4);
  u16*   kkb   = (u16*)alloc((size_t)L_SEQ * HDIM * 2);
  float* partial = (float*)alloc((size_t)L_SEQ * 4);
  float* sa = (float*)alloc((size_t)WKV_C * EDIM * 4);
  float* sb = (float*)alloc((size_t)WKV_C * EDIM * 4);
  float* sp = (float*)alloc((size_t)WKV_C * EDIM * 4);

  // converted-weight region: all-layers upfront if ws allows, else per-layer
  size_t remain = (ws_size > off) ? ws_size - off : 0;
  const size_t bigNeed = (5 * EE * NLAY + 2 * EH * NLAY + EE) * 2 + 8 * 256;
  const bool big = remain >= bigNeed;
  const int NB = big ? NLAY : 1;
  u16* wWk   = (u16*)alloc(EE * NB * 2);
  u16* wWv   = (u16*)alloc(EE * NB * 2);
  u16* wWr   = (u16*)alloc(EE * NB * 2);
  u16* wWo   = (u16*)alloc(EE * NB * 2);
  u16* wcmWr = (u16*)alloc(EE * NB * 2);
  u16* wcmWk = (u16*)alloc(EH * NB * 2);
  u16* wcmWv = (u16*)alloc(EH * NB * 2);
  u16* wneck = big ? (u16*)alloc(EE * 2) : wWk;

  const dim3 blk(256);
  const dim3 gE((L_SEQ * EDIM) / 256);
  const dim3 gemmE(EDIM / 128, L_SEQ / 128);
  const dim3 gemmE3(EDIM / 128, L_SEQ / 128, 3);
  const dim3 gemmH(HDIM / 128, L_SEQ / 128);
  const dim3 gWkv((WKV_C * EDIM) / 256);
  const dim3 gScan(EDIM / 256);

  const dim3 tcEE(EDIM / 32, EDIM / 32, NB);
  const dim3 tcEH(HDIM / 32, EDIM / 32, NB);  // cm_Wk: [E,H]
  const dim3 tcHE(EDIM / 32, HDIM / 32, NB);  // cm_Wv: [H,E]

  if (big) {
    k_tconv<<<tcEE, blk, 0, stream>>>(tm_Wk, wWk, EDIM, EDIM);
    k_tconv<<<tcEE, blk, 0, stream>>>(tm_Wv, wWv, EDIM, EDIM);
    k_tconv<<<tcEE, blk, 0, stream>>>(tm_Wr, wWr, EDIM, EDIM);
    k_tconv<<<tcEE, blk, 0, stream>>>(tm_Wo, wWo, EDIM, EDIM);
    k_tconv<<<tcEE, blk, 0, stream>>>(cm_Wr, wcmWr, EDIM, EDIM);
    k_tconv<<<tcEH, blk, 0, stream>>>(cm_Wk, wcmWk, EDIM, HDIM);
    k_tconv<<<tcHE, blk, 0, stream>>>(cm_Wv, wcmWv, HDIM, EDIM);
    k_tconv<<<dim3(EDIM / 32, EDIM / 32, 1), blk, 0, stream>>>(neck_W, wneck, EDIM, EDIM);
  }

  k_embed<<<gE, blk, 0, stream>>>(s, embed, x);
  for (int l = 0; l < NLAY; ++l) {
    size_t oE  = (size_t)l * EDIM;
    size_t oEE = (size_t)l * EE;
    size_t oEH = (size_t)l * EH;
    size_t wE  = big ? oEE : 0;
    size_t wH  = big ? oEH : 0;
    if (!big) {
      k_tconv<<<dim3(EDIM / 32, EDIM / 32, 1), blk, 0, stream>>>(tm_Wk + oEE, wWk, EDIM, EDIM);
      k_tconv<<<dim3(EDIM / 32, EDIM / 32, 1), blk, 0, stream>>>(tm_Wv + oEE, wWv, EDIM, EDIM);
      k_tconv<<<dim3(EDIM / 32, EDIM / 32, 1), blk, 0, stream>>>(tm_Wr + oEE, wWr, EDIM, EDIM);
      k_tconv<<<dim3(EDIM / 32, EDIM / 32, 1), blk, 0, stream>>>(tm_Wo + oEE, wWo, EDIM, EDIM);
      k_tconv<<<dim3(EDIM / 32, EDIM / 32, 1), blk, 0, stream>>>(cm_Wr + oEE, wcmWr, EDIM, EDIM);
      k_tconv<<<dim3(HDIM / 32, EDIM / 32, 1), blk, 0, stream>>>(cm_Wk + oEH, wcmWk, EDIM, HDIM);
      k_tconv<<<dim3(EDIM / 32, HDIM / 32, 1), blk, 0, stream>>>(cm_Wv + oEH, wcmWv, HDIM, EDIM);
    }
    // --- TimeMixing ---
    k_mix3<<<gE, blk, 0, stream>>>(x, tm_mk + oE, tm_mv + oE, tm_mr + oE, kxb, vxb, rxb);
    k_gemm3<<<gemmE3, blk, 0, stream>>>(kxb, vxb, rxb, wWk + wE, wWv + wE, wWr + wE,
                                        kf, vf, rpre, EDIM, EDIM);
    k_wkv_pass1<<<gWkv, blk, 0, stream>>>(kf, vf, tm_decay + oE, sa, sb, sp);
    k_wkv_scan<<<gScan, blk, 0, stream>>>(tm_decay + oE, sa, sb, sp);
    k_wkv_pass2<<<gWkv, blk, 0, stream>>>(kf, vf, tm_first + oE, tm_decay + oE,
                                          sa, sb, sp, wkvf);
    k_gate_mul<<<gE, blk, 0, stream>>>(rpre, wkvf, vxb);
    k_gemm<1><<<gemmE, blk, 0, stream>>>(vxb, wWo + wE, x, EDIM, EDIM);
    // --- ChannelMixing ---
    k_mix2<<<gE, blk, 0, stream>>>(x, cm_mk + oE, cm_mr + oE, kxb, rxb);
    k_gemm<2><<<gemmH, blk, 0, stream>>>(kxb, wcmWk + wH, kkb, HDIM, EDIM);
    k_gemm<0><<<gemmE, blk, 0, stream>>>(rxb, wcmWr + wE, rpre, EDIM, EDIM);
    k_gemm<0><<<gemmE, blk, 0, stream>>>(kkb, wcmWv + wH, wkvf, EDIM, HDIM);
    k_gate_add<<<gE, blk, 0, stream>>>(x, rpre, wkvf);
  }
  // --- Neck + Head ---
  if (!big) k_tconv<<<dim3(EDIM / 32, EDIM / 32, 1), blk, 0, stream>>>(neck_W, wneck, EDIM, EDIM);
  k_cast<<<gE, blk, 0, stream>>>(x, kxb);
  k_gemm<0><<<gemmE, blk, 0, stream>>>(kxb, wneck, kf, EDIM, EDIM);
  k_gelu<<<gE, blk, 0, stream>>>(kf, neck_b, vxb);
  k_head<<<dim3(L_SEQ), blk, 0, stream>>>(vxb, head_W, s, partial);
  k_reduce<<<dim3(1), blk, 0, stream>>>(partial, (float*)d_out);

  (void)in_sizes; (void)n_in; (void)out_size;
}

// Round 3
// 2965.829 us; speedup vs baseline: 3.8030x; 1.0699x over previous
//
#include <hip/hip_runtime.h>
#include <stdint.h>

#define L_SEQ 4096
#define EDIM  1024
#define HDIM  4096
#define NLAY  8
#define WKV_C 128  // chunks
#define WKV_T 32   // tokens per chunk

typedef unsigned short u16;
typedef __attribute__((ext_vector_type(8))) short short8;
typedef __attribute__((ext_vector_type(4))) float f32x4;

static __device__ __forceinline__ u16 f2b(float f) {
  union { float f; uint32_t u; } a; a.f = f;
  uint32_t u = a.u;
  return (u16)((u + 0x7FFFu + ((u >> 16) & 1u)) >> 16);  // RNE
}
static __device__ __forceinline__ float b2f(u16 b) {
  union { uint32_t u; float f; } a; a.u = ((uint32_t)b) << 16;
  return a.f;
}

static __device__ __forceinline__ void gld_lds16(const void* g, void* l) {
  __builtin_amdgcn_global_load_lds(
      (const __attribute__((address_space(1))) void*)g,
      (__attribute__((address_space(3))) void*)l, 16, 0, 0);
}

template <int N> static __device__ __forceinline__ void wait_vmcnt() {
  if constexpr (N == 0)      asm volatile("s_waitcnt vmcnt(0)" ::: "memory");
  else if constexpr (N == 4) asm volatile("s_waitcnt vmcnt(4)" ::: "memory");
  else                       asm volatile("s_waitcnt vmcnt(8)" ::: "memory");
}

// ---------------- elementwise ----------------

__global__ void k_embed(const int* __restrict__ s, const float* __restrict__ embed,
                        float* __restrict__ x) {
  int i = blockIdx.x * blockDim.x + threadIdx.x;
  int t = i >> 10, e = i & 1023;
  int tok = (t == 0) ? 0 : s[t - 1];
  x[i] = embed[tok * EDIM + e];
}

__global__ void k_mix3(const float* __restrict__ x,
                       const float* __restrict__ mk, const float* __restrict__ mv,
                       const float* __restrict__ mr,
                       u16* __restrict__ kx, u16* __restrict__ vx, u16* __restrict__ rx) {
  int i = blockIdx.x * blockDim.x + threadIdx.x;
  int e = i & 1023;
  float xc = x[i];
  float xs = (i >= EDIM) ? x[i - EDIM] : 0.f;
  float a = mk[e]; kx[i] = f2b(xc * a + xs * (1.f - a));
  a = mv[e];       vx[i] = f2b(xc * a + xs * (1.f - a));
  a = mr[e];       rx[i] = f2b(xc * a + xs * (1.f - a));
}

__global__ void k_mix2(const float* __restrict__ x,
                       const float* __restrict__ mk, const float* __restrict__ mr,
                       u16* __restrict__ kx, u16* __restrict__ rx) {
  int i = blockIdx.x * blockDim.x + threadIdx.x;
  int e = i & 1023;
  float xc = x[i];
  float xs = (i >= EDIM) ? x[i - EDIM] : 0.f;
  float a = mk[e]; kx[i] = f2b(xc * a + xs * (1.f - a));
  a = mr[e];       rx[i] = f2b(xc * a + xs * (1.f - a));
}

__global__ void k_gate_mul(const float* __restrict__ rpre, const float* __restrict__ wkv,
                           u16* __restrict__ outb) {
  int i = blockIdx.x * blockDim.x + threadIdx.x;
  float r = 1.f / (1.f + __expf(-rpre[i]));
  outb[i] = f2b(r * wkv[i]);
}

__global__ void k_gate_add(float* __restrict__ x, const float* __restrict__ rpre,
                           const float* __restrict__ t) {
  int i = blockIdx.x * blockDim.x + threadIdx.x;
  float r = 1.f / (1.f + __expf(-rpre[i]));
  x[i] += r * t[i];
}

__global__ void k_cast(const float* __restrict__ x, u16* __restrict__ o) {
  int i = blockIdx.x * blockDim.x + threadIdx.x;
  o[i] = f2b(x[i]);
}

__global__ void k_gelu(const float* __restrict__ p, const float* __restrict__ b,
                       u16* __restrict__ o) {
  int i = blockIdx.x * blockDim.x + threadIdx.x;
  int e = i & 1023;
  float v = p[i] + b[e];
  float c = 0.7978845608028654f * (v + 0.044715f * v * v * v);
  float g = 0.5f * v * (1.f + tanhf(c));
  o[i] = f2b(g);
}

// transpose + f32->bf16: src [K][N] f32 (batched by z), dst [N][K] bf16
__global__ __launch_bounds__(256)
void k_tconv(const float* __restrict__ src, u16* __restrict__ dst, int K, int N) {
  __shared__ float tile[32][33];
  const float* s = src + (size_t)blockIdx.z * K * N;
  u16* d = dst + (size_t)blockIdx.z * K * N;
  int n0 = blockIdx.x * 32, k0 = blockIdx.y * 32;
  int tx = threadIdx.x & 31, ty = threadIdx.x >> 5;  // 32 x 8
#pragma unroll
  for (int i = 0; i < 32; i += 8)
    tile[ty + i][tx] = s[(size_t)(k0 + ty + i) * N + n0 + tx];
  __syncthreads();
#pragma unroll
  for (int i = 0; i < 32; i += 8)
    d[(size_t)(n0 + ty + i) * K + k0 + tx] = f2b(tile[tx][ty + i]);
}

// ---------------- GEMM: C[M,N] = A_bf16[M,K] @ Bt_bf16[N,K]^T ----------------
// depth-3 pipelined, counted vmcnt, XOR-swizzled LDS (linear gld_lds dest,
// inverse-swizzled global source, swizzled ds_read).
// EPI: 0 = store f32, 1 = C += f32, 2 = store bf16 of relu(v)^2
template <int EPI>
__device__ __forceinline__
void gemm_body(const u16* __restrict__ A, const u16* __restrict__ Bt,
               void* __restrict__ Cv, int N, int K, int bm, int bn) {
  __shared__ __align__(16) u16 As[3][128 * 32];
  __shared__ __align__(16) u16 Bs[3][128 * 32];
  const int tid = threadIdx.x, lane = tid & 63, w = tid >> 6;
  const int wr = w >> 1, wc = w & 1;
  const int l16 = lane & 15, lhi = lane >> 4;

  f32x4 acc[4][4];
#pragma unroll
  for (int a = 0; a < 4; ++a)
#pragma unroll
    for (int b = 0; b < 4; ++b)
#pragma unroll
      for (int r = 0; r < 4; ++r) acc[a][b][r] = 0.f;

  const size_t rowBytes = (size_t)K * 2;
  const int NT = K >> 5;

  // staging geometry: LDS byte off (linear dest) = w*2048 + i*1024 + lane*16
  // global source column gets the inverse swizzle (XOR is an involution)
  int srow[2], scb[2];
#pragma unroll
  for (int i = 0; i < 2; ++i) {
    int off = w * 2048 + i * 1024 + lane * 16;
    srow[i] = off >> 6;
    scb[i] = (off & 63) ^ ((srow[i] & 3) << 4);
  }

  auto stage = [&](int t, int buf) {
    int kb = t * 64;  // byte offset along K
#pragma unroll
    for (int i = 0; i < 2; ++i) {
      gld_lds16((const char*)A + (size_t)(bm + srow[i]) * rowBytes + kb + scb[i],
                &As[buf][(w * 2048 + i * 1024) / 2]);
      gld_lds16((const char*)Bt + (size_t)(bn + srow[i]) * rowBytes + kb + scb[i],
                &Bs[buf][(w * 2048 + i * 1024) / 2]);
    }
  };

  // per-lane swizzled read offsets (u16 units) within an 8KB tile
  int aoff[4], boff[4];
#pragma unroll
  for (int mi = 0; mi < 4; ++mi) {
    int r = wr * 64 + mi * 16 + l16;
    aoff[mi] = r * 32 + (((lhi * 16) ^ ((r & 3) << 4)) >> 1);
    r = wc * 64 + mi * 16 + l16;
    boff[mi] = r * 32 + (((lhi * 16) ^ ((r & 3) << 4)) >> 1);
  }

  stage(0, 0);
  stage(1, 1);
  for (int t = 0; t < NT; ++t) {
    const int cur = t % 3;
    const int nxt = t + 2;
    if (nxt < NT) stage(nxt, nxt % 3);
    // counted wait: 2 tile-pairs in flight steady-state (4 loads each)
    if (nxt < NT)           wait_vmcnt<8>();
    else if (t + 1 < NT)    wait_vmcnt<4>();
    else                    wait_vmcnt<0>();
    __builtin_amdgcn_s_barrier();   // all waves' step-t loads arrived
    short8 af[4], bfr[4];
#pragma unroll
    for (int mi = 0; mi < 4; ++mi)
      af[mi] = *reinterpret_cast<const short8*>(&As[cur][aoff[mi]]);
#pragma unroll
    for (int ni = 0; ni < 4; ++ni)
      bfr[ni] = *reinterpret_cast<const short8*>(&Bs[cur][boff[ni]]);
    asm volatile("s_waitcnt lgkmcnt(0)" ::: "memory");
    __builtin_amdgcn_sched_barrier(0);
    __builtin_amdgcn_s_barrier();   // reads done; buf[cur] may be overwritten next iter
#pragma unroll
    for (int mi = 0; mi < 4; ++mi)
#pragma unroll
      for (int ni = 0; ni < 4; ++ni)
        acc[mi][ni] = __builtin_amdgcn_mfma_f32_16x16x32_bf16(af[mi], bfr[ni], acc[mi][ni], 0, 0, 0);
  }
#pragma unroll
  for (int mi = 0; mi < 4; ++mi)
#pragma unroll
    for (int ni = 0; ni < 4; ++ni)
#pragma unroll
      for (int r = 0; r < 4; ++r) {
        int row = bm + wr * 64 + mi * 16 + lhi * 4 + r;
        int col = bn + wc * 64 + ni * 16 + l16;
        size_t o = (size_t)row * N + col;
        float v = acc[mi][ni][r];
        if constexpr (EPI == 0) ((float*)Cv)[o] = v;
        else if constexpr (EPI == 1) ((float*)Cv)[o] += v;
        else { v = fmaxf(v, 0.f); ((u16*)Cv)[o] = f2b(v * v); }
      }
}

template <int EPI>
__global__ __launch_bounds__(256)
void k_gemm(const u16* __restrict__ A, const u16* __restrict__ Bt,
            void* __restrict__ Cv, int N, int K) {
  gemm_body<EPI>(A, Bt, Cv, N, K, blockIdx.y * 128, blockIdx.x * 128);
}

__global__ __launch_bounds__(256)
void k_gemm3(const u16* __restrict__ A0, const u16* __restrict__ A1, const u16* __restrict__ A2,
             const u16* __restrict__ B0, const u16* __restrict__ B1, const u16* __restrict__ B2,
             float* __restrict__ C0, float* __restrict__ C1, float* __restrict__ C2,
             int N, int K) {
  const u16* A = (blockIdx.z == 0) ? A0 : (blockIdx.z == 1) ? A1 : A2;
  const u16* B = (blockIdx.z == 0) ? B0 : (blockIdx.z == 1) ? B1 : B2;
  float*     C = (blockIdx.z == 0) ? C0 : (blockIdx.z == 1) ? C1 : C2;
  gemm_body<0>(A, B, C, N, K, blockIdx.y * 128, blockIdx.x * 128);
}

// ---------------- chunk-parallel WKV ----------------

__global__ void k_wkv_pass1(const float* __restrict__ k, const float* __restrict__ v,
                            const float* __restrict__ w_,
                            float* __restrict__ sa, float* __restrict__ sb,
                            float* __restrict__ sp) {
  int id = blockIdx.x * blockDim.x + threadIdx.x;  // over C*E
  int e = id & 1023, c = id >> 10;
  float D = __expf(w_[e]);
  float aa = 0.f, bb = 0.f, pp = -__builtin_inff();
  const float* kp = k + (size_t)c * WKV_T * EDIM + e;
  const float* vp = v + (size_t)c * WKV_T * EDIM + e;
#pragma unroll 4
  for (int i = 0; i < WKV_T; ++i) {
    float kk = kp[i * EDIM], vv = vp[i * EDIM];
    float ww = pp - D;
    float p2 = fmaxf(ww, kk);
    float e1 = __expf(ww - p2), e2 = __expf(kk - p2);
    aa = e1 * aa + e2 * vv;
    bb = e1 * bb + e2;
    pp = p2;
  }
  sa[id] = aa; sb[id] = bb; sp[id] = pp;
}

__global__ void k_wkv_scan(const float* __restrict__ w_,
                           float* __restrict__ sa, float* __restrict__ sb,
                           float* __restrict__ sp) {
  int e = blockIdx.x * blockDim.x + threadIdx.x;  // over E
  float DT = __expf(w_[e]) * (float)WKV_T;
  float A = 0.f, B = 0.f, P = -__builtin_inff();
  for (int c = 0; c < WKV_C; ++c) {
    int idx = c * EDIM + e;
    float a = sa[idx], b = sb[idx], q = sp[idx];
    sa[idx] = A; sb[idx] = B; sp[idx] = P;
    float shift = P - DT;
    float pn = fmaxf(shift, q);
    float w1 = __expf(shift - pn), w2 = __expf(q - pn);
    A = w1 * A + w2 * a;
    B = w1 * B + w2 * b;
    P = pn;
  }
}

__global__ void k_wkv_pass2(const float* __restrict__ k, const float* __restrict__ v,
                            const float* __restrict__ u_, const float* __restrict__ w_,
                            const float* __restrict__ sa, const float* __restrict__ sb,
                            const float* __restrict__ sp, float* __restrict__ out) {
  int id = blockIdx.x * blockDim.x + threadIdx.x;  // over C*E
  int e = id & 1023, c = id >> 10;
  float u = u_[e];
  float D = __expf(w_[e]);
  float aa = sa[id], bb = sb[id], pp = sp[id];
  const size_t base = (size_t)c * WKV_T * EDIM + e;
  const float* kp = k + base;
  const float* vp = v + base;
  float* op = out + base;
#pragma unroll 4
  for (int i = 0; i < WKV_T; ++i) {
    float kk = kp[i * EDIM], vv = vp[i * EDIM];
    float ww = u + kk;
    float p = fmaxf(pp, ww);
    float e1 = __expf(pp - p), e2 = __expf(ww - p);
    op[i * EDIM] = (e1 * aa + e2 * vv) / (e1 * bb + e2);
    float w2s = pp - D;
    float p2 = fmaxf(w2s, kk);
    float e1b = __expf(w2s - p2), e2b = __expf(kk - p2);
    aa = e1b * aa + e2b * vv;
    bb = e1b * bb + e2b;
    pp = p2;
  }
}

// ---------------- head ----------------

__global__ __launch_bounds__(256)
void k_head(const u16* __restrict__ h, const float* __restrict__ W,
            const int* __restrict__ s, float* __restrict__ partial) {
  int t = blockIdx.x, tid = threadIdx.x;
  float a0 = 0.f, a1 = 0.f, a2 = 0.f, a3 = 0.f;
  for (int e = tid; e < EDIM; e += 256) {
    float hv = b2f(h[t * EDIM + e]);
    const float4 wv = *reinterpret_cast<const float4*>(W + e * 4);
    a0 += hv * wv.x; a1 += hv * wv.y; a2 += hv * wv.z; a3 += hv * wv.w;
  }
#pragma unroll
  for (int off = 32; off > 0; off >>= 1) {
    a0 += __shfl_down(a0, off, 64);
    a1 += __shfl_down(a1, off, 64);
    a2 += __shfl_down(a2, off, 64);
    a3 += __shfl_down(a3, off, 64);
  }
  __shared__ float sm[4][4];
  int w = tid >> 6, lane = tid & 63;
  if (lane == 0) { sm[w][0] = a0; sm[w][1] = a1; sm[w][2] = a2; sm[w][3] = a3; }
  __syncthreads();
  if (tid == 0) {
    float lg[4];
#pragma unroll
    for (int j = 0; j < 4; ++j) lg[j] = sm[0][j] + sm[1][j] + sm[2][j] + sm[3][j];
    float m = fmaxf(fmaxf(lg[0], lg[1]), fmaxf(lg[2], lg[3]));
    float sum = expf(lg[0] - m) + expf(lg[1] - m) + expf(lg[2] - m) + expf(lg[3] - m);
    partial[t] = 0.5f * (lg[s[t]] - m - logf(sum));
  }
}

__global__ __launch_bounds__(256)
void k_reduce(const float* __restrict__ partial, float* __restrict__ out) {
  int tid = threadIdx.x;
  float a = 0.f;
  for (int j = tid; j < L_SEQ; j += 256) a += partial[j];
#pragma unroll
  for (int off = 32; off > 0; off >>= 1) a += __shfl_down(a, off, 64);
  __shared__ float sm[4];
  if ((tid & 63) == 0) sm[tid >> 6] = a;
  __syncthreads();
  if (tid == 0) out[0] = sm[0] + sm[1] + sm[2] + sm[3];
}

// ---------------- host ----------------

extern "C" void kernel_launch(void* const* d_in, const int* in_sizes, int n_in,
                              void* d_out, int out_size, void* d_ws, size_t ws_size,
                              hipStream_t stream) {
  const int*   s        = (const int*)d_in[0];
  const float* embed    = (const float*)d_in[1];
  const float* tm_first = (const float*)d_in[2];
  const float* tm_decay = (const float*)d_in[3];
  const float* tm_mk    = (const float*)d_in[4];
  const float* tm_mv    = (const float*)d_in[5];
  const float* tm_mr    = (const float*)d_in[6];
  const float* tm_Wk    = (const float*)d_in[7];
  const float* tm_Wv    = (const float*)d_in[8];
  const float* tm_Wr    = (const float*)d_in[9];
  const float* tm_Wo    = (const float*)d_in[10];
  const float* cm_mk    = (const float*)d_in[11];
  const float* cm_mr    = (const float*)d_in[12];
  const float* cm_Wk    = (const float*)d_in[13];
  const float* cm_Wr    = (const float*)d_in[14];
  const float* cm_Wv    = (const float*)d_in[15];
  const float* neck_W   = (const float*)d_in[16];
  const float* neck_b   = (const float*)d_in[17];
  const float* head_W   = (const float*)d_in[18];

  char* ws = (char*)d_ws;
  size_t off = 0;
  auto alloc = [&](size_t bytes) { char* p = ws + off; off += (bytes + 255) & ~(size_t)255; return p; };
  const size_t LE4 = (size_t)L_SEQ * EDIM * 4, LE2 = (size_t)L_SEQ * EDIM * 2;
  const size_t EE  = (size_t)EDIM * EDIM, EH = (size_t)EDIM * HDIM;

  float* x     = (float*)alloc(LE4);
  u16*   kxb   = (u16*)alloc(LE2);
  u16*   vxb   = (u16*)alloc(LE2);
  u16*   rxb   = (u16*)alloc(LE2);
  float* kf    = (float*)alloc(LE4);
  float* vf    = (float*)alloc(LE4);
  float* rpre  = (float*)alloc(LE4);
  float* wkvf  = (float*)alloc(LE4);
  u16*   kkb   = (u16*)alloc((size_t)L_SEQ * HDIM * 2);
  float* partial = (float*)alloc((size_t)L_SEQ * 4);
  float* sa = (float*)alloc((size_t)WKV_C * EDIM * 4);
  float* sb = (float*)alloc((size_t)WKV_C * EDIM * 4);
  float* sp = (float*)alloc((size_t)WKV_C * EDIM * 4);

  size_t remain = (ws_size > off) ? ws_size - off : 0;
  const size_t bigNeed = (5 * EE * NLAY + 2 * EH * NLAY + EE) * 2 + 16 * 256;
  const bool big = remain >= bigNeed;
  const int NB = big ? NLAY : 1;
  u16* wWk   = (u16*)alloc(EE * NB * 2);
  u16* wWv   = (u16*)alloc(EE * NB * 2);
  u16* wWr   = (u16*)alloc(EE * NB * 2);
  u16* wWo   = (u16*)alloc(EE * NB * 2);
  u16* wcmWr = (u16*)alloc(EE * NB * 2);
  u16* wcmWk = (u16*)alloc(EH * NB * 2);
  u16* wcmWv = (u16*)alloc(EH * NB * 2);
  u16* wneck = big ? (u16*)alloc(EE * 2) : wWk;

  const dim3 blk(256);
  const dim3 gE((L_SEQ * EDIM) / 256);
  const dim3 gemmE(EDIM / 128, L_SEQ / 128);
  const dim3 gemmE3(EDIM / 128, L_SEQ / 128, 3);
  const dim3 gemmH(HDIM / 128, L_SEQ / 128);
  const dim3 gWkv((WKV_C * EDIM) / 256);
  const dim3 gScan(EDIM / 256);

  const dim3 tcEE(EDIM / 32, EDIM / 32, NB);
  const dim3 tcEH(HDIM / 32, EDIM / 32, NB);
  const dim3 tcHE(EDIM / 32, HDIM / 32, NB);

  if (big) {
    k_tconv<<<tcEE, blk, 0, stream>>>(tm_Wk, wWk, EDIM, EDIM);
    k_tconv<<<tcEE, blk, 0, stream>>>(tm_Wv, wWv, EDIM, EDIM);
    k_tconv<<<tcEE, blk, 0, stream>>>(tm_Wr, wWr, EDIM, EDIM);
    k_tconv<<<tcEE, blk, 0, stream>>>(tm_Wo, wWo, EDIM, EDIM);
    k_tconv<<<tcEE, blk, 0, stream>>>(cm_Wr, wcmWr, EDIM, EDIM);
    k_tconv<<<tcEH, blk, 0, stream>>>(cm_Wk, wcmWk, EDIM, HDIM);
    k_tconv<<<tcHE, blk, 0, stream>>>(cm_Wv, wcmWv, HDIM, EDIM);
    k_tconv<<<dim3(EDIM / 32, EDIM / 32, 1), blk, 0, stream>>>(neck_W, wneck, EDIM, EDIM);
  }

  k_embed<<<gE, blk, 0, stream>>>(s, embed, x);
  for (int l = 0; l < NLAY; ++l) {
    size_t oE  = (size_t)l * EDIM;
    size_t oEE = (size_t)l * EE;
    size_t oEH = (size_t)l * EH;
    size_t wE  = big ? oEE : 0;
    size_t wH  = big ? oEH : 0;
    if (!big) {
      k_tconv<<<dim3(EDIM / 32, EDIM / 32, 1), blk, 0, stream>>>(tm_Wk + oEE, wWk, EDIM, EDIM);
      k_tconv<<<dim3(EDIM / 32, EDIM / 32, 1), blk, 0, stream>>>(tm_Wv + oEE, wWv, EDIM, EDIM);
      k_tconv<<<dim3(EDIM / 32, EDIM / 32, 1), blk, 0, stream>>>(tm_Wr + oEE, wWr, EDIM, EDIM);
      k_tconv<<<dim3(EDIM / 32, EDIM / 32, 1), blk, 0, stream>>>(tm_Wo + oEE, wWo, EDIM, EDIM);
      k_tconv<<<dim3(EDIM / 32, EDIM / 32, 1), blk, 0, stream>>>(cm_Wr + oEE, wcmWr, EDIM, EDIM);
      k_tconv<<<dim3(HDIM / 32, EDIM / 32, 1), blk, 0, stream>>>(cm_Wk + oEH, wcmWk, EDIM, HDIM);
      k_tconv<<<dim3(EDIM / 32, HDIM / 32, 1), blk, 0, stream>>>(cm_Wv + oEH, wcmWv, HDIM, EDIM);
    }
    // --- TimeMixing ---
    k_mix3<<<gE, blk, 0, stream>>>(x, tm_mk + oE, tm_mv + oE, tm_mr + oE, kxb, vxb, rxb);
    k_gemm3<<<gemmE3, blk, 0, stream>>>(kxb, vxb, rxb, wWk + wE, wWv + wE, wWr + wE,
                                        kf, vf, rpre, EDIM, EDIM);
    k_wkv_pass1<<<gWkv, blk, 0, stream>>>(kf, vf, tm_decay + oE, sa, sb, sp);
    k_wkv_scan<<<gScan, blk, 0, stream>>>(tm_decay + oE, sa, sb, sp);
    k_wkv_pass2<<<gWkv, blk, 0, stream>>>(kf, vf, tm_first + oE, tm_decay + oE,
                                          sa, sb, sp, wkvf);
    k_gate_mul<<<gE, blk, 0, stream>>>(rpre, wkvf, vxb);
    k_gemm<1><<<gemmE, blk, 0, stream>>>(vxb, wWo + wE, x, EDIM, EDIM);
    // --- ChannelMixing ---
    k_mix2<<<gE, blk, 0, stream>>>(x, cm_mk + oE, cm_mr + oE, kxb, rxb);
    k_gemm<2><<<gemmH, blk, 0, stream>>>(kxb, wcmWk + wH, kkb, HDIM, EDIM);
    k_gemm<0><<<gemmE, blk, 0, stream>>>(rxb, wcmWr + wE, rpre, EDIM, EDIM);
    k_gemm<0><<<gemmE, blk, 0, stream>>>(kkb, wcmWv + wH, wkvf, EDIM, HDIM);
    k_gate_add<<<gE, blk, 0, stream>>>(x, rpre, wkvf);
  }
  // --- Neck + Head ---
  if (!big) k_tconv<<<dim3(EDIM / 32, EDIM / 32, 1), blk, 0, stream>>>(neck_W, wneck, EDIM, EDIM);
  k_cast<<<gE, blk, 0, stream>>>(x, kxb);
  k_gemm<0><<<gemmE, blk, 0, stream>>>(kxb, wneck, kf, EDIM, EDIM);
  k_gelu<<<gE, blk, 0, stream>>>(kf, neck_b, vxb);
  k_head<<<dim3(L_SEQ), blk, 0, stream>>>(vxb, head_W, s, partial);
  k_reduce<<<dim3(1), blk, 0, stream>>>(partial, (float*)d_out);

  (void)in_sizes; (void)n_in; (void)out_size;
}

// Round 4
// 2439.432 us; speedup vs baseline: 4.6237x; 1.2158x over previous
//
#include <hip/hip_runtime.h>
#include <stdint.h>

#define L_SEQ 4096
#define EDIM  1024
#define HDIM  4096
#define NLAY  8
#define WKV_C 128  // chunks
#define WKV_T 32   // tokens per chunk

typedef unsigned short u16;
typedef __attribute__((ext_vector_type(8))) short short8;
typedef __attribute__((ext_vector_type(4))) float f32x4;
typedef __attribute__((ext_vector_type(4))) unsigned short us4;

static __device__ __forceinline__ u16 f2b(float f) {
  union { float f; uint32_t u; } a; a.f = f;
  uint32_t u = a.u;
  return (u16)((u + 0x7FFFu + ((u >> 16) & 1u)) >> 16);  // RNE
}
static __device__ __forceinline__ float b2f(u16 b) {
  union { uint32_t u; float f; } a; a.u = ((uint32_t)b) << 16;
  return a.f;
}

static __device__ __forceinline__ void gld_lds16(const void* g, void* l) {
  __builtin_amdgcn_global_load_lds(
      (const __attribute__((address_space(1))) void*)g,
      (__attribute__((address_space(3))) void*)l, 16, 0, 0);
}

// ---------------- elementwise (all x4 vectorized) ----------------

__global__ void k_embed(const int* __restrict__ s, const float* __restrict__ embed,
                        float* __restrict__ x) {
  int i = (blockIdx.x * blockDim.x + threadIdx.x) * 4;
  int t = i >> 10, e = i & 1023;
  int tok = (t == 0) ? 0 : s[t - 1];
  *reinterpret_cast<float4*>(&x[i]) =
      *reinterpret_cast<const float4*>(&embed[tok * EDIM + e]);
}

__global__ void k_mix3(const float* __restrict__ x,
                       const float* __restrict__ mk, const float* __restrict__ mv,
                       const float* __restrict__ mr,
                       u16* __restrict__ kx, u16* __restrict__ vx, u16* __restrict__ rx) {
  int i = (blockIdx.x * blockDim.x + threadIdx.x) * 4;
  int e = i & 1023;
  float4 xc = *reinterpret_cast<const float4*>(&x[i]);
  float4 xs = make_float4(0.f, 0.f, 0.f, 0.f);
  if (i >= EDIM) xs = *reinterpret_cast<const float4*>(&x[i - EDIM]);
  float4 m; us4 o;
  m = *reinterpret_cast<const float4*>(&mk[e]);
  o.x = f2b(xc.x * m.x + xs.x * (1.f - m.x));
  o.y = f2b(xc.y * m.y + xs.y * (1.f - m.y));
  o.z = f2b(xc.z * m.z + xs.z * (1.f - m.z));
  o.w = f2b(xc.w * m.w + xs.w * (1.f - m.w));
  *reinterpret_cast<us4*>(&kx[i]) = o;
  m = *reinterpret_cast<const float4*>(&mv[e]);
  o.x = f2b(xc.x * m.x + xs.x * (1.f - m.x));
  o.y = f2b(xc.y * m.y + xs.y * (1.f - m.y));
  o.z = f2b(xc.z * m.z + xs.z * (1.f - m.z));
  o.w = f2b(xc.w * m.w + xs.w * (1.f - m.w));
  *reinterpret_cast<us4*>(&vx[i]) = o;
  m = *reinterpret_cast<const float4*>(&mr[e]);
  o.x = f2b(xc.x * m.x + xs.x * (1.f - m.x));
  o.y = f2b(xc.y * m.y + xs.y * (1.f - m.y));
  o.z = f2b(xc.z * m.z + xs.z * (1.f - m.z));
  o.w = f2b(xc.w * m.w + xs.w * (1.f - m.w));
  *reinterpret_cast<us4*>(&rx[i]) = o;
}

__global__ void k_mix2(const float* __restrict__ x,
                       const float* __restrict__ mk, const float* __restrict__ mr,
                       u16* __restrict__ kx, u16* __restrict__ rx) {
  int i = (blockIdx.x * blockDim.x + threadIdx.x) * 4;
  int e = i & 1023;
  float4 xc = *reinterpret_cast<const float4*>(&x[i]);
  float4 xs = make_float4(0.f, 0.f, 0.f, 0.f);
  if (i >= EDIM) xs = *reinterpret_cast<const float4*>(&x[i - EDIM]);
  float4 m; us4 o;
  m = *reinterpret_cast<const float4*>(&mk[e]);
  o.x = f2b(xc.x * m.x + xs.x * (1.f - m.x));
  o.y = f2b(xc.y * m.y + xs.y * (1.f - m.y));
  o.z = f2b(xc.z * m.z + xs.z * (1.f - m.z));
  o.w = f2b(xc.w * m.w + xs.w * (1.f - m.w));
  *reinterpret_cast<us4*>(&kx[i]) = o;
  m = *reinterpret_cast<const float4*>(&mr[e]);
  o.x = f2b(xc.x * m.x + xs.x * (1.f - m.x));
  o.y = f2b(xc.y * m.y + xs.y * (1.f - m.y));
  o.z = f2b(xc.z * m.z + xs.z * (1.f - m.z));
  o.w = f2b(xc.w * m.w + xs.w * (1.f - m.w));
  *reinterpret_cast<us4*>(&rx[i]) = o;
}

__global__ void k_gate_mul(const float* __restrict__ rpre, const float* __restrict__ wkv,
                           u16* __restrict__ outb) {
  int i = (blockIdx.x * blockDim.x + threadIdx.x) * 4;
  float4 r = *reinterpret_cast<const float4*>(&rpre[i]);
  float4 v = *reinterpret_cast<const float4*>(&wkv[i]);
  us4 o;
  o.x = f2b(v.x / (1.f + __expf(-r.x)));
  o.y = f2b(v.y / (1.f + __expf(-r.y)));
  o.z = f2b(v.z / (1.f + __expf(-r.z)));
  o.w = f2b(v.w / (1.f + __expf(-r.w)));
  *reinterpret_cast<us4*>(&outb[i]) = o;
}

// x += P0 + P1 (tm_Wo split-K reduce)
__global__ void k_add2(float* __restrict__ x, const float* __restrict__ P) {
  int i = (blockIdx.x * blockDim.x + threadIdx.x) * 4;
  const size_t LE = (size_t)L_SEQ * EDIM;
  float4 a = *reinterpret_cast<const float4*>(&P[i]);
  float4 b = *reinterpret_cast<const float4*>(&P[i + LE]);
  float4 xv = *reinterpret_cast<float4*>(&x[i]);
  xv.x += a.x + b.x; xv.y += a.y + b.y; xv.z += a.z + b.z; xv.w += a.w + b.w;
  *reinterpret_cast<float4*>(&x[i]) = xv;
}

// x += sigmoid(R0+R1) * (V0+V1)
__global__ void k_gate_add2(float* __restrict__ x, const float* __restrict__ R,
                            const float* __restrict__ V) {
  int i = (blockIdx.x * blockDim.x + threadIdx.x) * 4;
  const size_t LE = (size_t)L_SEQ * EDIM;
  float4 r0 = *reinterpret_cast<const float4*>(&R[i]);
  float4 r1 = *reinterpret_cast<const float4*>(&R[i + LE]);
  float4 v0 = *reinterpret_cast<const float4*>(&V[i]);
  float4 v1 = *reinterpret_cast<const float4*>(&V[i + LE]);
  float4 xv = *reinterpret_cast<float4*>(&x[i]);
  xv.x += (v0.x + v1.x) / (1.f + __expf(-(r0.x + r1.x)));
  xv.y += (v0.y + v1.y) / (1.f + __expf(-(r0.y + r1.y)));
  xv.z += (v0.z + v1.z) / (1.f + __expf(-(r0.z + r1.z)));
  xv.w += (v0.w + v1.w) / (1.f + __expf(-(r0.w + r1.w)));
  *reinterpret_cast<float4*>(&x[i]) = xv;
}

__global__ void k_cast(const float* __restrict__ x, u16* __restrict__ o) {
  int i = (blockIdx.x * blockDim.x + threadIdx.x) * 4;
  float4 v = *reinterpret_cast<const float4*>(&x[i]);
  us4 ov;
  ov.x = f2b(v.x); ov.y = f2b(v.y); ov.z = f2b(v.z); ov.w = f2b(v.w);
  *reinterpret_cast<us4*>(&o[i]) = ov;
}

static __device__ __forceinline__ float gelu1(float v) {
  float c = 0.7978845608028654f * (v + 0.044715f * v * v * v);
  return 0.5f * v * (1.f + tanhf(c));
}

// o = bf16(gelu(P0+P1+b))
__global__ void k_gelu2(const float* __restrict__ P, const float* __restrict__ b,
                        u16* __restrict__ o) {
  int i = (blockIdx.x * blockDim.x + threadIdx.x) * 4;
  int e = i & 1023;
  const size_t LE = (size_t)L_SEQ * EDIM;
  float4 p0 = *reinterpret_cast<const float4*>(&P[i]);
  float4 p1 = *reinterpret_cast<const float4*>(&P[i + LE]);
  float4 bb = *reinterpret_cast<const float4*>(&b[e]);
  us4 ov;
  ov.x = f2b(gelu1(p0.x + p1.x + bb.x));
  ov.y = f2b(gelu1(p0.y + p1.y + bb.y));
  ov.z = f2b(gelu1(p0.z + p1.z + bb.z));
  ov.w = f2b(gelu1(p0.w + p1.w + bb.w));
  *reinterpret_cast<us4*>(&o[i]) = ov;
}

// transpose + f32->bf16: src [K][N] f32 (batched by z), dst [N][K] bf16, 64x64 tiles
__global__ __launch_bounds__(256)
void k_tconv(const float* __restrict__ src, u16* __restrict__ dst, int K, int N) {
  __shared__ float tile[64][65];
  const float* s = src + (size_t)blockIdx.z * K * N;
  u16* d = dst + (size_t)blockIdx.z * K * N;
  int n0 = blockIdx.x * 64, k0 = blockIdx.y * 64;
  int tx = threadIdx.x & 15, ty = threadIdx.x >> 4;  // 16 x 16
#pragma unroll
  for (int i = 0; i < 4; ++i) {
    int kr = ty + i * 16;
    float4 v = *reinterpret_cast<const float4*>(&s[(size_t)(k0 + kr) * N + n0 + tx * 4]);
    tile[kr][tx * 4 + 0] = v.x; tile[kr][tx * 4 + 1] = v.y;
    tile[kr][tx * 4 + 2] = v.z; tile[kr][tx * 4 + 3] = v.w;
  }
  __syncthreads();
#pragma unroll
  for (int i = 0; i < 4; ++i) {
    int nr = ty + i * 16;
    us4 o;
    o.x = f2b(tile[tx * 4 + 0][nr]);
    o.y = f2b(tile[tx * 4 + 1][nr]);
    o.z = f2b(tile[tx * 4 + 2][nr]);
    o.w = f2b(tile[tx * 4 + 3][nr]);
    *reinterpret_cast<us4*>(&d[(size_t)(n0 + nr) * K + k0 + tx * 4]) = o;
  }
}

// ---------------- GEMM: C[M,N] = A_bf16[M,ldk-rows] @ Bt_bf16[N,ldk]^T ----------------
// depth-3 pipeline, ONE barrier/iter, counted vmcnt, conflict-free swizzle
// slot(r, chunk) = (chunk + (r>>1)) & 3   (involution pair applied on source+read)
// EPI: 0 = store f32, 2 = store bf16 of relu(v)^2
template <int EPI>
__device__ __forceinline__
void gemm_body(const u16* __restrict__ A, const u16* __restrict__ Bt,
               void* __restrict__ Cv, int N, int ldk, int klen, int bm, int bn) {
  __shared__ __align__(16) u16 As[3][128 * 32];
  __shared__ __align__(16) u16 Bs[3][128 * 32];
  const int tid = threadIdx.x, lane = tid & 63, w = tid >> 6;
  const int wr = w >> 1, wc = w & 1;
  const int l16 = lane & 15, lhi = lane >> 4;

  f32x4 acc[4][4];
#pragma unroll
  for (int a = 0; a < 4; ++a)
#pragma unroll
    for (int b = 0; b < 4; ++b)
#pragma unroll
      for (int r = 0; r < 4; ++r) acc[a][b][r] = 0.f;

  const size_t rowBytes = (size_t)ldk * 2;
  const int NT = klen >> 5;

  // staging: linear LDS dest (wave base + lane*16 implicit); swizzled global source
  int srow[2], scb[2], ldso[2];
#pragma unroll
  for (int i = 0; i < 2; ++i) {
    int off = w * 2048 + i * 1024 + lane * 16;
    int r = off >> 6, sl = (off >> 4) & 3;
    srow[i] = r;
    scb[i] = ((sl - (r >> 1)) & 3) << 4;
    ldso[i] = (w * 2048 + i * 1024) >> 1;
  }

  auto stage = [&](int t, int buf) {
    int kb = t * 64;  // bytes along K
#pragma unroll
    for (int i = 0; i < 2; ++i) {
      gld_lds16((const char*)A + (size_t)(bm + srow[i]) * rowBytes + kb + scb[i],
                &As[buf][ldso[i]]);
      gld_lds16((const char*)Bt + (size_t)(bn + srow[i]) * rowBytes + kb + scb[i],
                &Bs[buf][ldso[i]]);
    }
  };

  // swizzled per-lane read offsets (u16 units)
  int aoff[4], boff[4];
#pragma unroll
  for (int mi = 0; mi < 4; ++mi) {
    int r = wr * 64 + mi * 16 + l16;
    aoff[mi] = r * 32 + (((lhi + (r >> 1)) & 3) << 3);
    r = wc * 64 + mi * 16 + l16;
    boff[mi] = r * 32 + (((lhi + (r >> 1)) & 3) << 3);
  }

  stage(0, 0);
  stage(1, 1);
  for (int t = 0; t < NT; ++t) {
    const int cur = t % 3;
    if (t + 1 < NT) asm volatile("s_waitcnt vmcnt(4)" ::: "memory");
    else            asm volatile("s_waitcnt vmcnt(0)" ::: "memory");
    __builtin_amdgcn_s_barrier();          // everyone's tile-t loads arrived
    __builtin_amdgcn_sched_barrier(0);     // keep reads below the barrier
    short8 af[4], bfr[4];
#pragma unroll
    for (int mi = 0; mi < 4; ++mi)
      af[mi] = *reinterpret_cast<const short8*>(&As[cur][aoff[mi]]);
#pragma unroll
    for (int ni = 0; ni < 4; ++ni)
      bfr[ni] = *reinterpret_cast<const short8*>(&Bs[cur][boff[ni]]);
    if (t + 2 < NT) stage(t + 2, (t + 2) % 3);  // overwrites buf[(t-1)%3]: safe post-barrier
    asm volatile("s_waitcnt lgkmcnt(0)" ::: "memory");
    __builtin_amdgcn_sched_barrier(0);
#pragma unroll
    for (int mi = 0; mi < 4; ++mi)
#pragma unroll
      for (int ni = 0; ni < 4; ++ni)
        acc[mi][ni] = __builtin_amdgcn_mfma_f32_16x16x32_bf16(af[mi], bfr[ni], acc[mi][ni], 0, 0, 0);
  }
#pragma unroll
  for (int mi = 0; mi < 4; ++mi)
#pragma unroll
    for (int ni = 0; ni < 4; ++ni)
#pragma unroll
      for (int r = 0; r < 4; ++r) {
        int row = bm + wr * 64 + mi * 16 + lhi * 4 + r;
        int col = bn + wc * 64 + ni * 16 + l16;
        size_t o = (size_t)row * N + col;
        float v = acc[mi][ni][r];
        if constexpr (EPI == 0) ((float*)Cv)[o] = v;
        else { v = fmaxf(v, 0.f); ((u16*)Cv)[o] = f2b(v * v); }
      }
}

template <int EPI>
__global__ __launch_bounds__(256)
void k_gemm(const u16* __restrict__ A, const u16* __restrict__ Bt,
            void* __restrict__ Cv, int N, int K) {
  gemm_body<EPI>(A, Bt, Cv, N, K, K, blockIdx.y * 128, blockIdx.x * 128);
}

// split-K x2: z selects K-half; writes f32 partial P + z*L*N
__global__ __launch_bounds__(256)
void k_gemm_sk2(const u16* __restrict__ A, const u16* __restrict__ Bt,
                float* __restrict__ P, int N, int K) {
  const int z = blockIdx.z, klen = K >> 1;
  gemm_body<0>(A + z * klen, Bt + z * klen, P + (size_t)z * L_SEQ * N,
               N, K, klen, blockIdx.y * 128, blockIdx.x * 128);
}

// batched k/v/r
__global__ __launch_bounds__(256)
void k_gemm3(const u16* __restrict__ A0, const u16* __restrict__ A1, const u16* __restrict__ A2,
             const u16* __restrict__ B0, const u16* __restrict__ B1, const u16* __restrict__ B2,
             float* __restrict__ C0, float* __restrict__ C1, float* __restrict__ C2,
             int N, int K) {
  const u16* A = (blockIdx.z == 0) ? A0 : (blockIdx.z == 1) ? A1 : A2;
  const u16* B = (blockIdx.z == 0) ? B0 : (blockIdx.z == 1) ? B1 : B2;
  float*     C = (blockIdx.z == 0) ? C0 : (blockIdx.z == 1) ? C1 : C2;
  gemm_body<0>(A, B, C, N, K, K, blockIdx.y * 128, blockIdx.x * 128);
}

// ---------------- chunk-parallel WKV ----------------

__global__ void k_wkv_pass1(const float* __restrict__ k, const float* __restrict__ v,
                            const float* __restrict__ w_,
                            float* __restrict__ sa, float* __restrict__ sb,
                            float* __restrict__ sp) {
  int id = blockIdx.x * blockDim.x + threadIdx.x;
  int e = id & 1023, c = id >> 10;
  float D = __expf(w_[e]);
  float aa = 0.f, bb = 0.f, pp = -__builtin_inff();
  const float* kp = k + (size_t)c * WKV_T * EDIM + e;
  const float* vp = v + (size_t)c * WKV_T * EDIM + e;
#pragma unroll 4
  for (int i = 0; i < WKV_T; ++i) {
    float kk = kp[i * EDIM], vv = vp[i * EDIM];
    float ww = pp - D;
    float p2 = fmaxf(ww, kk);
    float e1 = __expf(ww - p2), e2 = __expf(kk - p2);
    aa = e1 * aa + e2 * vv;
    bb = e1 * bb + e2;
    pp = p2;
  }
  sa[id] = aa; sb[id] = bb; sp[id] = pp;
}

// exclusive scan (ping-pong out buffers, prefetched loads)
__global__ void k_wkv_scan(const float* __restrict__ w_,
                           const float* __restrict__ sa, const float* __restrict__ sb,
                           const float* __restrict__ sp,
                           float* __restrict__ oa, float* __restrict__ ob,
                           float* __restrict__ op) {
  int e = blockIdx.x * blockDim.x + threadIdx.x;
  float DT = __expf(w_[e]) * (float)WKV_T;
  float A = 0.f, B = 0.f, P = -__builtin_inff();
  float na = sa[e], nb = sb[e], np = sp[e];
  for (int c = 0; c < WKV_C; ++c) {
    float a = na, b = nb, q = np;
    if (c + 1 < WKV_C) {
      int idx = (c + 1) * EDIM + e;
      na = sa[idx]; nb = sb[idx]; np = sp[idx];
    }
    int idx = c * EDIM + e;
    oa[idx] = A; ob[idx] = B; op[idx] = P;
    float shift = P - DT;
    float pn = fmaxf(shift, q);
    float w1 = __expf(shift - pn), w2 = __expf(q - pn);
    A = w1 * A + w2 * a;
    B = w1 * B + w2 * b;
    P = pn;
  }
}

__global__ void k_wkv_pass2(const float* __restrict__ k, const float* __restrict__ v,
                            const float* __restrict__ u_, const float* __restrict__ w_,
                            const float* __restrict__ sa, const float* __restrict__ sb,
                            const float* __restrict__ sp, float* __restrict__ out) {
  int id = blockIdx.x * blockDim.x + threadIdx.x;
  int e = id & 1023, c = id >> 10;
  float u = u_[e];
  float D = __expf(w_[e]);
  float aa = sa[id], bb = sb[id], pp = sp[id];
  const size_t base = (size_t)c * WKV_T * EDIM + e;
  const float* kp = k + base;
  const float* vp = v + base;
  float* op = out + base;
#pragma unroll 4
  for (int i = 0; i < WKV_T; ++i) {
    float kk = kp[i * EDIM], vv = vp[i * EDIM];
    float ww = u + kk;
    float p = fmaxf(pp, ww);
    float e1 = __expf(pp - p), e2 = __expf(ww - p);
    op[i * EDIM] = (e1 * aa + e2 * vv) / (e1 * bb + e2);
    float w2s = pp - D;
    float p2 = fmaxf(w2s, kk);
    float e1b = __expf(w2s - p2), e2b = __expf(kk - p2);
    aa = e1b * aa + e2b * vv;
    bb = e1b * bb + e2b;
    pp = p2;
  }
}

// ---------------- head ----------------

__global__ __launch_bounds__(256)
void k_head(const u16* __restrict__ h, const float* __restrict__ W,
            const int* __restrict__ s, float* __restrict__ partial) {
  int t = blockIdx.x, tid = threadIdx.x;
  float a0 = 0.f, a1 = 0.f, a2 = 0.f, a3 = 0.f;
  for (int e = tid; e < EDIM; e += 256) {
    float hv = b2f(h[t * EDIM + e]);
    const float4 wv = *reinterpret_cast<const float4*>(W + e * 4);
    a0 += hv * wv.x; a1 += hv * wv.y; a2 += hv * wv.z; a3 += hv * wv.w;
  }
#pragma unroll
  for (int off = 32; off > 0; off >>= 1) {
    a0 += __shfl_down(a0, off, 64);
    a1 += __shfl_down(a1, off, 64);
    a2 += __shfl_down(a2, off, 64);
    a3 += __shfl_down(a3, off, 64);
  }
  __shared__ float sm[4][4];
  int w = tid >> 6, lane = tid & 63;
  if (lane == 0) { sm[w][0] = a0; sm[w][1] = a1; sm[w][2] = a2; sm[w][3] = a3; }
  __syncthreads();
  if (tid == 0) {
    float lg[4];
#pragma unroll
    for (int j = 0; j < 4; ++j) lg[j] = sm[0][j] + sm[1][j] + sm[2][j] + sm[3][j];
    float m = fmaxf(fmaxf(lg[0], lg[1]), fmaxf(lg[2], lg[3]));
    float sum = expf(lg[0] - m) + expf(lg[1] - m) + expf(lg[2] - m) + expf(lg[3] - m);
    partial[t] = 0.5f * (lg[s[t]] - m - logf(sum));
  }
}

__global__ __launch_bounds__(256)
void k_reduce(const float* __restrict__ partial, float* __restrict__ out) {
  int tid = threadIdx.x;
  float a = 0.f;
  for (int j = tid; j < L_SEQ; j += 256) a += partial[j];
#pragma unroll
  for (int off = 32; off > 0; off >>= 1) a += __shfl_down(a, off, 64);
  __shared__ float sm[4];
  if ((tid & 63) == 0) sm[tid >> 6] = a;
  __syncthreads();
  if (tid == 0) out[0] = sm[0] + sm[1] + sm[2] + sm[3];
}

// ---------------- host ----------------

extern "C" void kernel_launch(void* const* d_in, const int* in_sizes, int n_in,
                              void* d_out, int out_size, void* d_ws, size_t ws_size,
                              hipStream_t stream) {
  const int*   s        = (const int*)d_in[0];
  const float* embed    = (const float*)d_in[1];
  const float* tm_first = (const float*)d_in[2];
  const float* tm_decay = (const float*)d_in[3];
  const float* tm_mk    = (const float*)d_in[4];
  const float* tm_mv    = (const float*)d_in[5];
  const float* tm_mr    = (const float*)d_in[6];
  const float* tm_Wk    = (const float*)d_in[7];
  const float* tm_Wv    = (const float*)d_in[8];
  const float* tm_Wr    = (const float*)d_in[9];
  const float* tm_Wo    = (const float*)d_in[10];
  const float* cm_mk    = (const float*)d_in[11];
  const float* cm_mr    = (const float*)d_in[12];
  const float* cm_Wk    = (const float*)d_in[13];
  const float* cm_Wr    = (const float*)d_in[14];
  const float* cm_Wv    = (const float*)d_in[15];
  const float* neck_W   = (const float*)d_in[16];
  const float* neck_b   = (const float*)d_in[17];
  const float* head_W   = (const float*)d_in[18];

  char* ws = (char*)d_ws;
  size_t off = 0;
  auto alloc = [&](size_t bytes) { char* p = ws + off; off += (bytes + 255) & ~(size_t)255; return p; };
  const size_t LE4 = (size_t)L_SEQ * EDIM * 4, LE2 = (size_t)L_SEQ * EDIM * 2;
  const size_t EE  = (size_t)EDIM * EDIM, EH = (size_t)EDIM * HDIM;

  float* x     = (float*)alloc(LE4);
  u16*   kxb   = (u16*)alloc(LE2);
  u16*   vxb   = (u16*)alloc(LE2);
  u16*   rxb   = (u16*)alloc(LE2);
  float* kf    = (float*)alloc(LE4);
  float* vf    = (float*)alloc(LE4);
  float* rpre  = (float*)alloc(LE4);
  float* wkvf  = (float*)alloc(LE4);
  u16*   kkb   = (u16*)alloc((size_t)L_SEQ * HDIM * 2);
  float* PA    = (float*)alloc(2 * LE4);   // split-K partials (Wo / cm_Wr / neck)
  float* PB    = (float*)alloc(2 * LE4);   // split-K partials (cm_Wv)
  float* partial = (float*)alloc((size_t)L_SEQ * 4);
  float* sa  = (float*)alloc((size_t)WKV_C * EDIM * 4);
  float* sb  = (float*)alloc((size_t)WKV_C * EDIM * 4);
  float* sp  = (float*)alloc((size_t)WKV_C * EDIM * 4);
  float* sa2 = (float*)alloc((size_t)WKV_C * EDIM * 4);
  float* sb2 = (float*)alloc((size_t)WKV_C * EDIM * 4);
  float* sp2 = (float*)alloc((size_t)WKV_C * EDIM * 4);

  size_t remain = (ws_size > off) ? ws_size - off : 0;
  const size_t bigNeed = (5 * EE * NLAY + 2 * EH * NLAY + EE) * 2 + 16 * 256;
  const bool big = remain >= bigNeed;
  const int NB = big ? NLAY : 1;
  u16* wWk   = (u16*)alloc(EE * NB * 2);
  u16* wWv   = (u16*)alloc(EE * NB * 2);
  u16* wWr   = (u16*)alloc(EE * NB * 2);
  u16* wWo   = (u16*)alloc(EE * NB * 2);
  u16* wcmWr = (u16*)alloc(EE * NB * 2);
  u16* wcmWk = (u16*)alloc(EH * NB * 2);
  u16* wcmWv = (u16*)alloc(EH * NB * 2);
  u16* wneck = big ? (u16*)alloc(EE * 2) : wWk;

  const dim3 blk(256);
  const dim3 gE4((L_SEQ * EDIM) / 1024);
  const dim3 gemmE(EDIM / 128, L_SEQ / 128);
  const dim3 gemmE3(EDIM / 128, L_SEQ / 128, 3);
  const dim3 gemmSK(EDIM / 128, L_SEQ / 128, 2);
  const dim3 gemmH(HDIM / 128, L_SEQ / 128);
  const dim3 gWkv((WKV_C * EDIM) / 256);
  const dim3 gScan(EDIM / 256);

  const dim3 tcEE(EDIM / 64, EDIM / 64, NB);
  const dim3 tcEH(HDIM / 64, EDIM / 64, NB);
  const dim3 tcHE(EDIM / 64, HDIM / 64, NB);

  if (big) {
    k_tconv<<<tcEE, blk, 0, stream>>>(tm_Wk, wWk, EDIM, EDIM);
    k_tconv<<<tcEE, blk, 0, stream>>>(tm_Wv, wWv, EDIM, EDIM);
    k_tconv<<<tcEE, blk, 0, stream>>>(tm_Wr, wWr, EDIM, EDIM);
    k_tconv<<<tcEE, blk, 0, stream>>>(tm_Wo, wWo, EDIM, EDIM);
    k_tconv<<<tcEE, blk, 0, stream>>>(cm_Wr, wcmWr, EDIM, EDIM);
    k_tconv<<<tcEH, blk, 0, stream>>>(cm_Wk, wcmWk, EDIM, HDIM);
    k_tconv<<<tcHE, blk, 0, stream>>>(cm_Wv, wcmWv, HDIM, EDIM);
    k_tconv<<<dim3(EDIM / 64, EDIM / 64, 1), blk, 0, stream>>>(neck_W, wneck, EDIM, EDIM);
  }

  k_embed<<<gE4, blk, 0, stream>>>(s, embed, x);
  for (int l = 0; l < NLAY; ++l) {
    size_t oE  = (size_t)l * EDIM;
    size_t oEE = (size_t)l * EE;
    size_t oEH = (size_t)l * EH;
    size_t wE  = big ? oEE : 0;
    size_t wH  = big ? oEH : 0;
    if (!big) {
      k_tconv<<<dim3(EDIM / 64, EDIM / 64, 1), blk, 0, stream>>>(tm_Wk + oEE, wWk, EDIM, EDIM);
      k_tconv<<<dim3(EDIM / 64, EDIM / 64, 1), blk, 0, stream>>>(tm_Wv + oEE, wWv, EDIM, EDIM);
      k_tconv<<<dim3(EDIM / 64, EDIM / 64, 1), blk, 0, stream>>>(tm_Wr + oEE, wWr, EDIM, EDIM);
      k_tconv<<<dim3(EDIM / 64, EDIM / 64, 1), blk, 0, stream>>>(tm_Wo + oEE, wWo, EDIM, EDIM);
      k_tconv<<<dim3(EDIM / 64, EDIM / 64, 1), blk, 0, stream>>>(cm_Wr + oEE, wcmWr, EDIM, EDIM);
      k_tconv<<<dim3(HDIM / 64, EDIM / 64, 1), blk, 0, stream>>>(cm_Wk + oEH, wcmWk, EDIM, HDIM);
      k_tconv<<<dim3(EDIM / 64, HDIM / 64, 1), blk, 0, stream>>>(cm_Wv + oEH, wcmWv, HDIM, EDIM);
    }
    // --- TimeMixing ---
    k_mix3<<<gE4, blk, 0, stream>>>(x, tm_mk + oE, tm_mv + oE, tm_mr + oE, kxb, vxb, rxb);
    k_gemm3<<<gemmE3, blk, 0, stream>>>(kxb, vxb, rxb, wWk + wE, wWv + wE, wWr + wE,
                                        kf, vf, rpre, EDIM, EDIM);
    k_wkv_pass1<<<gWkv, blk, 0, stream>>>(kf, vf, tm_decay + oE, sa, sb, sp);
    k_wkv_scan<<<gScan, blk, 0, stream>>>(tm_decay + oE, sa, sb, sp, sa2, sb2, sp2);
    k_wkv_pass2<<<gWkv, blk, 0, stream>>>(kf, vf, tm_first + oE, tm_decay + oE,
                                          sa2, sb2, sp2, wkvf);
    k_gate_mul<<<gE4, blk, 0, stream>>>(rpre, wkvf, vxb);
    k_gemm_sk2<<<gemmSK, blk, 0, stream>>>(vxb, wWo + wE, PA, EDIM, EDIM);
    k_add2<<<gE4, blk, 0, stream>>>(x, PA);
    // --- ChannelMixing ---
    k_mix2<<<gE4, blk, 0, stream>>>(x, cm_mk + oE, cm_mr + oE, kxb, rxb);
    k_gemm<2><<<gemmH, blk, 0, stream>>>(kxb, wcmWk + wH, kkb, HDIM, EDIM);
    k_gemm_sk2<<<gemmSK, blk, 0, stream>>>(rxb, wcmWr + wE, PA, EDIM, EDIM);
    k_gemm_sk2<<<gemmSK, blk, 0, stream>>>(kkb, wcmWv + wH, PB, EDIM, HDIM);
    k_gate_add2<<<gE4, blk, 0, stream>>>(x, PA, PB);
  }
  // --- Neck + Head ---
  if (!big) k_tconv<<<dim3(EDIM / 64, EDIM / 64, 1), blk, 0, stream>>>(neck_W, wneck, EDIM, EDIM);
  k_cast<<<gE4, blk, 0, stream>>>(x, kxb);
  k_gemm_sk2<<<gemmSK, blk, 0, stream>>>(kxb, wneck, PA, EDIM, EDIM);
  k_gelu2<<<gE4, blk, 0, stream>>>(PA, neck_b, vxb);
  k_head<<<dim3(L_SEQ), blk, 0, stream>>>(vxb, head_W, s, partial);
  k_reduce<<<dim3(1), blk, 0, stream>>>(partial, (float*)d_out);

  (void)in_sizes; (void)n_in; (void)out_size;
}